// Round 2
// baseline (2119.818 us; speedup 1.0000x reference)
//
#include <hip/hip_runtime.h>
#include <hip/hip_bf16.h>

// B=16, D=256, H=64, W=64, S=4096, P=8, tokens T=64, E=D*64=16384
// All inputs/outputs are FLOAT32 (per reference). Intermediates bf16.
#define BB 16
#define SS 4096

__device__ __forceinline__ float bf2f(__hip_bfloat16 h) {
  return __bfloat162float(h);
}
__device__ __forceinline__ void bf16x8_to_f(uint4 u, float* f) {
  unsigned w[4] = {u.x, u.y, u.z, u.w};
#pragma unroll
  for (int i = 0; i < 4; ++i) {
    union { unsigned u; float f; } lo, hi;
    lo.u = (w[i] & 0xffffu) << 16;
    hi.u = w[i] & 0xffff0000u;
    f[2 * i] = lo.f;
    f[2 * i + 1] = hi.f;
  }
}

// ---------------------------------------------------------------------------
// K1: QKV 1x1-conv GEMM. out[b,o,s] = sum_c W[o,c] x[b,c,s] + bias[o]
// fp32 inputs -> bf16 outputs. grid (64 s-tiles, 4 o-tiles, B*3), block 256.
// ---------------------------------------------------------------------------
__global__ __launch_bounds__(256) void qkv_gemm(
    const float* __restrict__ x,
    const float* __restrict__ wq, const float* __restrict__ bq,
    const float* __restrict__ wk, const float* __restrict__ bk,
    const float* __restrict__ wv, const float* __restrict__ bv,
    __hip_bfloat16* __restrict__ qb, __hip_bfloat16* __restrict__ kb,
    __hip_bfloat16* __restrict__ vb) {
  __shared__ float Ws[32][65];  // [c][o]
  __shared__ float Xs[32][65];  // [c][s]
  const int which = blockIdx.z % 3;
  const int b = blockIdx.z / 3;
  const float* Wm = (which == 0) ? wq : (which == 1) ? wk : wv;
  const float* bias = (which == 0) ? bq : (which == 1) ? bk : bv;
  __hip_bfloat16* outb = (which == 0) ? qb : (which == 1) ? kb : vb;
  const int o0 = blockIdx.y * 64;
  const int s0 = blockIdx.x * 64;
  const int tid = threadIdx.x;
  const int to = tid >> 4;
  const int ts = tid & 15;
  float acc[4][4] = {};

  for (int c0 = 0; c0 < 256; c0 += 32) {
    {  // stage W tile 64(o) x 32(c): 8 floats per thread
      int o = tid >> 2;
      int cseg = (tid & 3) * 8;
      const float4* wp =
          reinterpret_cast<const float4*>(Wm + (o0 + o) * 256 + c0 + cseg);
      float4 u0 = wp[0], u1 = wp[1];
      Ws[cseg + 0][o] = u0.x; Ws[cseg + 1][o] = u0.y;
      Ws[cseg + 2][o] = u0.z; Ws[cseg + 3][o] = u0.w;
      Ws[cseg + 4][o] = u1.x; Ws[cseg + 5][o] = u1.y;
      Ws[cseg + 6][o] = u1.z; Ws[cseg + 7][o] = u1.w;
    }
    {  // stage X tile 32(c) x 64(s): 8 floats per thread
      int c = tid >> 3;
      int sseg = (tid & 7) * 8;
      const float4* xp = reinterpret_cast<const float4*>(
          x + ((size_t)(b * 256 + c0 + c)) * SS + s0 + sseg);
      float4 v0 = xp[0], v1 = xp[1];
      Xs[c][sseg + 0] = v0.x; Xs[c][sseg + 1] = v0.y;
      Xs[c][sseg + 2] = v0.z; Xs[c][sseg + 3] = v0.w;
      Xs[c][sseg + 4] = v1.x; Xs[c][sseg + 5] = v1.y;
      Xs[c][sseg + 6] = v1.z; Xs[c][sseg + 7] = v1.w;
    }
    __syncthreads();
#pragma unroll 8
    for (int k = 0; k < 32; ++k) {
      float a[4], xv[4];
#pragma unroll
      for (int i = 0; i < 4; ++i) a[i] = Ws[k][to * 4 + i];
#pragma unroll
      for (int j = 0; j < 4; ++j) xv[j] = Xs[k][ts * 4 + j];
#pragma unroll
      for (int i = 0; i < 4; ++i)
#pragma unroll
        for (int j = 0; j < 4; ++j) acc[i][j] += a[i] * xv[j];
    }
    __syncthreads();
  }
#pragma unroll
  for (int i = 0; i < 4; ++i) {
    int o = o0 + to * 4 + i;
    float bi = bias[o];
#pragma unroll
    for (int j = 0; j < 4; ++j) {
      int s = s0 + ts * 4 + j;
      outb[((size_t)(b * 256 + o)) * SS + s] = __float2bfloat16(acc[i][j] + bi);
    }
  }
}

// ---------------------------------------------------------------------------
// K2: raw scores[b,t,t'] = sum_e q[b,t,e]*k[b,t',e]  (unscaled, atomicAdd)
// grid (16 d-chunks, B), block 256. bf16 q,k.
// plane idx -> h=idx>>6, w=idx&63; t=(h>>3)*8+(w>>3), off=(h&7)*8+(w&7).
// ---------------------------------------------------------------------------
__global__ __launch_bounds__(256) void scores_kernel(
    const __hip_bfloat16* __restrict__ qb, const __hip_bfloat16* __restrict__ kb,
    float* __restrict__ attn) {
  __shared__ float qs[64 * 65];
  __shared__ float ks[64 * 65];
  const int b = blockIdx.y;
  const int d0 = blockIdx.x * 16;
  const int tid = threadIdx.x;
  const int tq = (tid >> 4) * 4;
  const int tk = (tid & 15) * 4;
  float acc[4][4] = {};

  for (int dd = 0; dd < 16; ++dd) {
    const int d = d0 + dd;
    const __hip_bfloat16* qp = qb + ((size_t)(b * 256 + d)) * SS;
    const __hip_bfloat16* kp = kb + ((size_t)(b * 256 + d)) * SS;
#pragma unroll
    for (int j = 0; j < 2; ++j) {
      int base = (j * 256 + tid) * 8;
      int h = base >> 6, w = base & 63;
      int t = (h >> 3) * 8 + (w >> 3);
      int off = (h & 7) * 8;
      float f[8];
      bf16x8_to_f(*reinterpret_cast<const uint4*>(qp + base), f);
#pragma unroll
      for (int e = 0; e < 8; ++e) qs[t * 65 + off + e] = f[e];
      bf16x8_to_f(*reinterpret_cast<const uint4*>(kp + base), f);
#pragma unroll
      for (int e = 0; e < 8; ++e) ks[t * 65 + off + e] = f[e];
    }
    __syncthreads();
#pragma unroll 8
    for (int off = 0; off < 64; ++off) {
      float a[4], bb[4];
#pragma unroll
      for (int i = 0; i < 4; ++i) a[i] = qs[(tq + i) * 65 + off];
#pragma unroll
      for (int j = 0; j < 4; ++j) bb[j] = ks[(tk + j) * 65 + off];
#pragma unroll
      for (int i = 0; i < 4; ++i)
#pragma unroll
        for (int j = 0; j < 4; ++j) acc[i][j] += a[i] * bb[j];
    }
    __syncthreads();
  }
#pragma unroll
  for (int i = 0; i < 4; ++i)
#pragma unroll
    for (int j = 0; j < 4; ++j)
      atomicAdd(&attn[(b * 64 + tq + i) * 64 + tk + j], acc[i][j]);
}

// ---------------------------------------------------------------------------
// K3: softmax over t' with scale 1/128. grid (64 t, B), block 64 (one wave).
// ---------------------------------------------------------------------------
__global__ __launch_bounds__(64) void softmax_kernel(float* __restrict__ attn) {
  const int t = blockIdx.x;
  const int b = blockIdx.y;
  const int lane = threadIdx.x;
  float* row = attn + (b * 64 + t) * 64;
  float v = row[lane] * 0.0078125f;  // 1/sqrt(16384)
  float m = v;
#pragma unroll
  for (int off = 32; off >= 1; off >>= 1) m = fmaxf(m, __shfl_xor(m, off));
  float e = __expf(v - m);
  float s = e;
#pragma unroll
  for (int off = 32; off >= 1; off >>= 1) s += __shfl_xor(s, off);
  row[lane] = e / s;
}

// ---------------------------------------------------------------------------
// K4: z[b,d,h,w] = sum_t' attn[b,t(h,w),t'] * v[b,d,h'(t'),w'(t')]
// grid (32 d-groups of 8, B), block 256. bf16 v (lives in d_out), bf16 z.
// ---------------------------------------------------------------------------
__global__ __launch_bounds__(256) void apply_attn(
    const float* __restrict__ attn, const __hip_bfloat16* __restrict__ vb,
    __hip_bfloat16* __restrict__ zb) {
  __shared__ float A[64 * 65];
  __shared__ float Vp[64 * 65];
  const int b = blockIdx.y;
  const int d0 = blockIdx.x * 8;
  const int tid = threadIdx.x;
#pragma unroll
  for (int j = 0; j < 16; ++j) {
    int idx = j * 256 + tid;
    A[(idx >> 6) * 65 + (idx & 63)] = attn[b * 4096 + idx];
  }
  const int t0 = (tid >> 4) * 4;
  const int f0 = (tid & 15) * 4;
  for (int ddv = 0; ddv < 8; ++ddv) {
    const int d = d0 + ddv;
    const __hip_bfloat16* vp = vb + ((size_t)(b * 256 + d)) * SS;
#pragma unroll
    for (int j = 0; j < 2; ++j) {
      int base = (j * 256 + tid) * 8;
      int h = base >> 6, w = base & 63;
      int t = (h >> 3) * 8 + (w >> 3);
      int off = (h & 7) * 8;
      float f[8];
      bf16x8_to_f(*reinterpret_cast<const uint4*>(vp + base), f);
#pragma unroll
      for (int e = 0; e < 8; ++e) Vp[t * 65 + off + e] = f[e];
    }
    __syncthreads();
    float acc[4][4] = {};
#pragma unroll 8
    for (int tp = 0; tp < 64; ++tp) {
      float a[4], vv[4];
#pragma unroll
      for (int i = 0; i < 4; ++i) a[i] = A[(t0 + i) * 65 + tp];
#pragma unroll
      for (int j = 0; j < 4; ++j) vv[j] = Vp[tp * 65 + f0 + j];
#pragma unroll
      for (int i = 0; i < 4; ++i)
#pragma unroll
        for (int j = 0; j < 4; ++j) acc[i][j] += a[i] * vv[j];
    }
#pragma unroll
    for (int i = 0; i < 4; ++i) {
      int t = t0 + i;
#pragma unroll
      for (int j = 0; j < 4; ++j) {
        int off = f0 + j;
        int h = (t >> 3) * 8 + (off >> 3);
        int w = (t & 7) * 8 + (off & 7);
        zb[((size_t)(b * 256 + d)) * SS + h * 64 + w] =
            __float2bfloat16(acc[i][j]);
      }
    }
    __syncthreads();
  }
}

// ---------------------------------------------------------------------------
// K5: 3x3 conv (pad 1) + BN(eval) + LeakyReLU(0.2). bf16 z in, fp32 out.
// grid (8 h-tiles, 16 o-tiles, B), block 256.
// ---------------------------------------------------------------------------
__global__ __launch_bounds__(256) void conv_bn_lrelu(
    const __hip_bfloat16* __restrict__ z, const float* __restrict__ wo,
    const float* __restrict__ bo, const float* __restrict__ gm,
    const float* __restrict__ bt, const float* __restrict__ mn,
    const float* __restrict__ vr, float* __restrict__ out) {
  __shared__ float zs[16][10][66];
  __shared__ float wt[16][16][9];
  const int h0 = blockIdx.x * 8;
  const int o0 = blockIdx.y * 16;
  const int b = blockIdx.z;
  const int tid = threadIdx.x;
  const int wi = tid & 63;
  const int og = tid >> 6;
  float acc[8][4] = {};

  for (int c0 = 0; c0 < 256; c0 += 16) {
    for (int idx = tid; idx < 16 * 10 * 66; idx += 256) {
      int cc = idx / 660;
      int rem = idx % 660;
      int r = rem / 66;
      int col = rem % 66 - 1;
      int hh = h0 - 1 + r;
      float v = 0.f;
      if (hh >= 0 && hh < 64 && col >= 0 && col < 64)
        v = bf2f(z[((size_t)(b * 256 + c0 + cc)) * SS + hh * 64 + col]);
      zs[cc][r][col + 1] = v;
    }
    for (int idx = tid; idx < 16 * 16 * 9; idx += 256) {
      int o = idx / 144;
      int rem = idx % 144;
      int c = rem / 9;
      int k = rem % 9;
      wt[o][c][k] = wo[((size_t)((o0 + o) * 256 + c0 + c)) * 9 + k];
    }
    __syncthreads();
    for (int cc = 0; cc < 16; ++cc) {
#pragma unroll
      for (int kh = 0; kh < 3; ++kh)
#pragma unroll
        for (int kw = 0; kw < 3; ++kw) {
          const int k = kh * 3 + kw;
          float wv[4];
#pragma unroll
          for (int i = 0; i < 4; ++i) wv[i] = wt[og * 4 + i][cc][k];
#pragma unroll
          for (int j = 0; j < 8; ++j) {
            float zv = zs[cc][j + kh][wi + kw];
#pragma unroll
            for (int i = 0; i < 4; ++i) acc[j][i] += wv[i] * zv;
          }
        }
    }
    __syncthreads();
  }
#pragma unroll
  for (int i = 0; i < 4; ++i) {
    int o = o0 + og * 4 + i;
    float sc = gm[o] * rsqrtf(vr[o] + 1e-5f);
    float sh = bt[o] + (bo[o] - mn[o]) * sc;
#pragma unroll
    for (int j = 0; j < 8; ++j) {
      float y = acc[j][i] * sc + sh;
      y = (y >= 0.f) ? y : 0.2f * y;
      out[((size_t)(b * 256 + o)) * SS + (h0 + j) * 64 + wi] = y;
    }
  }
}

extern "C" void kernel_launch(void* const* d_in, const int* in_sizes, int n_in,
                              void* d_out, int out_size, void* d_ws,
                              size_t ws_size, hipStream_t stream) {
  (void)in_sizes; (void)n_in; (void)out_size; (void)ws_size;
  const float* x  = (const float*)d_in[0];
  const float* wq = (const float*)d_in[1];
  const float* bq = (const float*)d_in[2];
  const float* wk = (const float*)d_in[3];
  const float* bk = (const float*)d_in[4];
  const float* wv = (const float*)d_in[5];
  const float* bv = (const float*)d_in[6];
  const float* wo = (const float*)d_in[7];
  const float* bo = (const float*)d_in[8];
  const float* gm = (const float*)d_in[9];
  const float* bt = (const float*)d_in[10];
  const float* mn = (const float*)d_in[11];
  const float* vr = (const float*)d_in[12];
  float* out = (float*)d_out;

  char* ws = (char*)d_ws;
  __hip_bfloat16* qb = (__hip_bfloat16*)(ws);             // 32 MB, reused as z
  __hip_bfloat16* kb = (__hip_bfloat16*)(ws + 33554432);  // 32 MB
  float* attn = (float*)(ws + 67108864);                  // 256 KB
  // v lives in d_out (bf16, first 32 MB); dead before K5 overwrites d_out.
  __hip_bfloat16* vb = (__hip_bfloat16*)d_out;

  hipMemsetAsync(attn, 0, BB * 64 * 64 * sizeof(float), stream);
  qkv_gemm<<<dim3(64, 4, BB * 3), 256, 0, stream>>>(x, wq, bq, wk, bk, wv, bv,
                                                    qb, kb, vb);
  scores_kernel<<<dim3(16, BB), 256, 0, stream>>>(qb, kb, attn);
  softmax_kernel<<<dim3(64, BB), 64, 0, stream>>>(attn);
  apply_attn<<<dim3(32, BB), 256, 0, stream>>>(attn, vb, qb /* z */);
  conv_bn_lrelu<<<dim3(8, 16, BB), 256, 0, stream>>>(qb, wo, bo, gm, bt, mn, vr,
                                                     out);
}

// Round 3
// 1041.219 us; speedup vs baseline: 2.0359x; 2.0359x over previous
//
#include <hip/hip_runtime.h>
#include <hip/hip_bf16.h>

// B=16, D=256, H=64, W=64, S=4096, P=8, tokens T=64, E=D*64=16384
// Inputs/outputs FLOAT32 (per reference). Intermediates bf16.
#define BB 16
#define SS 4096

typedef __attribute__((ext_vector_type(8))) short short8;
typedef __attribute__((ext_vector_type(4))) float float4v;

__device__ __forceinline__ float bf2f(__hip_bfloat16 h) {
  return __bfloat162float(h);
}
__device__ __forceinline__ void bf16x8_to_f(uint4 u, float* f) {
  unsigned w[4] = {u.x, u.y, u.z, u.w};
#pragma unroll
  for (int i = 0; i < 4; ++i) {
    union { unsigned u; float f; } lo, hi;
    lo.u = (w[i] & 0xffffu) << 16;
    hi.u = w[i] & 0xffff0000u;
    f[2 * i] = lo.f;
    f[2 * i + 1] = hi.f;
  }
}

// ---------------------------------------------------------------------------
// K1: QKV 1x1-conv GEMM. out[b,o,s] = sum_c W[o,c] x[b,c,s] + bias[o]
// fp32 in -> bf16 out (NCHW). grid (64,4,B*3), block 256.
// ---------------------------------------------------------------------------
__global__ __launch_bounds__(256) void qkv_gemm(
    const float* __restrict__ x,
    const float* __restrict__ wq, const float* __restrict__ bq,
    const float* __restrict__ wk, const float* __restrict__ bk,
    const float* __restrict__ wv, const float* __restrict__ bv,
    __hip_bfloat16* __restrict__ qb, __hip_bfloat16* __restrict__ kb,
    __hip_bfloat16* __restrict__ vb) {
  __shared__ float Ws[32][65];
  __shared__ float Xs[32][65];
  const int which = blockIdx.z % 3;
  const int b = blockIdx.z / 3;
  const float* Wm = (which == 0) ? wq : (which == 1) ? wk : wv;
  const float* bias = (which == 0) ? bq : (which == 1) ? bk : bv;
  __hip_bfloat16* outb = (which == 0) ? qb : (which == 1) ? kb : vb;
  const int o0 = blockIdx.y * 64;
  const int s0 = blockIdx.x * 64;
  const int tid = threadIdx.x;
  const int to = tid >> 4;
  const int ts = tid & 15;
  float acc[4][4] = {};

  for (int c0 = 0; c0 < 256; c0 += 32) {
    {
      int o = tid >> 2;
      int cseg = (tid & 3) * 8;
      const float4* wp =
          reinterpret_cast<const float4*>(Wm + (o0 + o) * 256 + c0 + cseg);
      float4 u0 = wp[0], u1 = wp[1];
      Ws[cseg + 0][o] = u0.x; Ws[cseg + 1][o] = u0.y;
      Ws[cseg + 2][o] = u0.z; Ws[cseg + 3][o] = u0.w;
      Ws[cseg + 4][o] = u1.x; Ws[cseg + 5][o] = u1.y;
      Ws[cseg + 6][o] = u1.z; Ws[cseg + 7][o] = u1.w;
    }
    {
      int c = tid >> 3;
      int sseg = (tid & 7) * 8;
      const float4* xp = reinterpret_cast<const float4*>(
          x + ((size_t)(b * 256 + c0 + c)) * SS + s0 + sseg);
      float4 v0 = xp[0], v1 = xp[1];
      Xs[c][sseg + 0] = v0.x; Xs[c][sseg + 1] = v0.y;
      Xs[c][sseg + 2] = v0.z; Xs[c][sseg + 3] = v0.w;
      Xs[c][sseg + 4] = v1.x; Xs[c][sseg + 5] = v1.y;
      Xs[c][sseg + 6] = v1.z; Xs[c][sseg + 7] = v1.w;
    }
    __syncthreads();
#pragma unroll 8
    for (int k = 0; k < 32; ++k) {
      float a[4], xv[4];
#pragma unroll
      for (int i = 0; i < 4; ++i) a[i] = Ws[k][to * 4 + i];
#pragma unroll
      for (int j = 0; j < 4; ++j) xv[j] = Xs[k][ts * 4 + j];
#pragma unroll
      for (int i = 0; i < 4; ++i)
#pragma unroll
        for (int j = 0; j < 4; ++j) acc[i][j] += a[i] * xv[j];
    }
    __syncthreads();
  }
#pragma unroll
  for (int i = 0; i < 4; ++i) {
    int o = o0 + to * 4 + i;
    float bi = bias[o];
#pragma unroll
    for (int j = 0; j < 4; ++j) {
      int s = s0 + ts * 4 + j;
      outb[((size_t)(b * 256 + o)) * SS + s] = __float2bfloat16(acc[i][j] + bi);
    }
  }
}

// ---------------------------------------------------------------------------
// K2: raw scores[b,t,t'] = sum_e q[b,t,e]*k[b,t',e] (unscaled, atomicAdd)
// ---------------------------------------------------------------------------
__global__ __launch_bounds__(256) void scores_kernel(
    const __hip_bfloat16* __restrict__ qb, const __hip_bfloat16* __restrict__ kb,
    float* __restrict__ attn) {
  __shared__ float qs[64 * 65];
  __shared__ float ks[64 * 65];
  const int b = blockIdx.y;
  const int d0 = blockIdx.x * 16;
  const int tid = threadIdx.x;
  const int tq = (tid >> 4) * 4;
  const int tk = (tid & 15) * 4;
  float acc[4][4] = {};

  for (int dd = 0; dd < 16; ++dd) {
    const int d = d0 + dd;
    const __hip_bfloat16* qp = qb + ((size_t)(b * 256 + d)) * SS;
    const __hip_bfloat16* kp = kb + ((size_t)(b * 256 + d)) * SS;
#pragma unroll
    for (int j = 0; j < 2; ++j) {
      int base = (j * 256 + tid) * 8;
      int h = base >> 6, w = base & 63;
      int t = (h >> 3) * 8 + (w >> 3);
      int off = (h & 7) * 8;
      float f[8];
      bf16x8_to_f(*reinterpret_cast<const uint4*>(qp + base), f);
#pragma unroll
      for (int e = 0; e < 8; ++e) qs[t * 65 + off + e] = f[e];
      bf16x8_to_f(*reinterpret_cast<const uint4*>(kp + base), f);
#pragma unroll
      for (int e = 0; e < 8; ++e) ks[t * 65 + off + e] = f[e];
    }
    __syncthreads();
#pragma unroll 8
    for (int off = 0; off < 64; ++off) {
      float a[4], bb[4];
#pragma unroll
      for (int i = 0; i < 4; ++i) a[i] = qs[(tq + i) * 65 + off];
#pragma unroll
      for (int j = 0; j < 4; ++j) bb[j] = ks[(tk + j) * 65 + off];
#pragma unroll
      for (int i = 0; i < 4; ++i)
#pragma unroll
        for (int j = 0; j < 4; ++j) acc[i][j] += a[i] * bb[j];
    }
    __syncthreads();
  }
#pragma unroll
  for (int i = 0; i < 4; ++i)
#pragma unroll
    for (int j = 0; j < 4; ++j)
      atomicAdd(&attn[(b * 64 + tq + i) * 64 + tk + j], acc[i][j]);
}

// ---------------------------------------------------------------------------
// K3: softmax over t' with scale 1/128. grid (64 t, B), block 64.
// ---------------------------------------------------------------------------
__global__ __launch_bounds__(64) void softmax_kernel(float* __restrict__ attn) {
  const int t = blockIdx.x;
  const int b = blockIdx.y;
  const int lane = threadIdx.x;
  float* row = attn + (b * 64 + t) * 64;
  float v = row[lane] * 0.0078125f;  // 1/sqrt(16384)
  float m = v;
#pragma unroll
  for (int off = 32; off >= 1; off >>= 1) m = fmaxf(m, __shfl_xor(m, off));
  float e = __expf(v - m);
  float s = e;
#pragma unroll
  for (int off = 32; off >= 1; off >>= 1) s += __shfl_xor(s, off);
  row[lane] = e / s;
}

// ---------------------------------------------------------------------------
// K4: z = attn @ v, written NHWC: z[((b*64+h)*64+w)*256 + d]  (bf16)
// ---------------------------------------------------------------------------
__global__ __launch_bounds__(256) void apply_attn(
    const float* __restrict__ attn, const __hip_bfloat16* __restrict__ vb,
    __hip_bfloat16* __restrict__ zb) {
  __shared__ float A[64 * 65];
  __shared__ float Vp[64 * 65];
  const int b = blockIdx.y;
  const int d0 = blockIdx.x * 8;
  const int tid = threadIdx.x;
#pragma unroll
  for (int j = 0; j < 16; ++j) {
    int idx = j * 256 + tid;
    A[(idx >> 6) * 65 + (idx & 63)] = attn[b * 4096 + idx];
  }
  const int t0 = (tid >> 4) * 4;
  const int f0 = (tid & 15) * 4;
  for (int ddv = 0; ddv < 8; ++ddv) {
    const int d = d0 + ddv;
    const __hip_bfloat16* vp = vb + ((size_t)(b * 256 + d)) * SS;
#pragma unroll
    for (int j = 0; j < 2; ++j) {
      int base = (j * 256 + tid) * 8;
      int h = base >> 6, w = base & 63;
      int t = (h >> 3) * 8 + (w >> 3);
      int off = (h & 7) * 8;
      float f[8];
      bf16x8_to_f(*reinterpret_cast<const uint4*>(vp + base), f);
#pragma unroll
      for (int e = 0; e < 8; ++e) Vp[t * 65 + off + e] = f[e];
    }
    __syncthreads();
    float acc[4][4] = {};
#pragma unroll 8
    for (int tp = 0; tp < 64; ++tp) {
      float a[4], vv[4];
#pragma unroll
      for (int i = 0; i < 4; ++i) a[i] = A[(t0 + i) * 65 + tp];
#pragma unroll
      for (int j = 0; j < 4; ++j) vv[j] = Vp[tp * 65 + f0 + j];
#pragma unroll
      for (int i = 0; i < 4; ++i)
#pragma unroll
        for (int j = 0; j < 4; ++j) acc[i][j] += a[i] * vv[j];
    }
#pragma unroll
    for (int i = 0; i < 4; ++i) {
      int t = t0 + i;
#pragma unroll
      for (int j = 0; j < 4; ++j) {
        int off = f0 + j;
        int h = (t >> 3) * 8 + (off >> 3);
        int w = (t & 7) * 8 + (off & 7);
        // NHWC
        zb[((size_t)((b * 64 + h) * 64 + w)) * 256 + d] =
            __float2bfloat16(acc[i][j]);
      }
    }
    __syncthreads();
  }
}

// ---------------------------------------------------------------------------
// K5a: weight prep: wo[o][c][3][3] fp32 -> bf16 blob in B-fragment order:
// blob[((tap*8+cb)*16+ob)*512 + lane*8 + j] = wo[o=ob*16+(lane&15)]
//                                               [c=cb*32+(lane>>4)*8+j][tap]
// ---------------------------------------------------------------------------
__global__ __launch_bounds__(256) void wprep(
    const float* __restrict__ wo, __hip_bfloat16* __restrict__ blob) {
  int chunk = blockIdx.x * 256 + threadIdx.x;  // 73728 = 9*8*16*64 exact
  int l = chunk & 63;
  int ob = (chunk >> 6) & 15;
  int cb = (chunk >> 10) & 7;
  int tap = chunk >> 13;
  int o = ob * 16 + (l & 15);
  int c0 = cb * 32 + (l >> 4) * 8;
  union { uint4 u; __hip_bfloat16 h[8]; } t;
#pragma unroll
  for (int j = 0; j < 8; ++j)
    t.h[j] = __float2bfloat16(wo[((size_t)(o * 256 + c0 + j)) * 9 + tap]);
  *reinterpret_cast<uint4*>(blob + (size_t)chunk * 8) = t.u;
}

// ---------------------------------------------------------------------------
// K5b: MFMA implicit-GEMM 3x3 conv + bias + BN + LeakyReLU.
// z NHWC bf16 in, fp32 NCHW out. One block per image row (b,h): M=64(w),
// N=256(o) split over 4 waves, K = 8 cblocks x 9 taps x 32c.
// D[o][w] = mfma(w_frag as A, z_frag as B): row=o, col=w -> w-contiguous
// stores. LDS: halo tile [3 rows][66 wpos][32c + 8 pad].
// ---------------------------------------------------------------------------
__global__ __launch_bounds__(256) void conv_mfma(
    const __hip_bfloat16* __restrict__ z, const __hip_bfloat16* __restrict__ blob,
    const float* __restrict__ bo, const float* __restrict__ gm,
    const float* __restrict__ bt, const float* __restrict__ mn,
    const float* __restrict__ vr, float* __restrict__ out) {
  __shared__ short zs[3 * 66 * 40];
  const int row = blockIdx.x;  // b*64 + h
  const int b = row >> 6, h = row & 63;
  const int tid = threadIdx.x;
  const int wave = tid >> 6, lane = tid & 63;
  const int q = lane >> 4, m = lane & 15;
  float4v acc[4][4] = {};  // [of][wf]

  for (int cb = 0; cb < 8; ++cb) {
    __syncthreads();  // previous-iter LDS reads done before restage
    for (int idx = tid; idx < 792; idx += 256) {  // 3*66*4 uint4 chunks
      int cg = idx & 3;
      int t2 = idx >> 2;
      int wpos = t2 % 66;
      int r = t2 / 66;
      int h_in = h - 1 + r;
      int w_in = wpos - 1;
      uint4 val = make_uint4(0u, 0u, 0u, 0u);
      if (h_in >= 0 && h_in < 64 && w_in >= 0 && w_in < 64)
        val = *reinterpret_cast<const uint4*>(
            z + ((size_t)((b * 64 + h_in) * 64 + w_in)) * 256 + cb * 32 + cg * 8);
      *reinterpret_cast<uint4*>(&zs[(r * 66 + wpos) * 40 + cg * 8]) = val;
    }
    __syncthreads();
    for (int tap = 0; tap < 9; ++tap) {
      const int kh = tap / 3, kw = tap % 3;
      short8 wf[4];
#pragma unroll
      for (int of = 0; of < 4; ++of) {
        int ob = wave * 4 + of;
        wf[of] = *reinterpret_cast<const short8*>(
            blob + ((size_t)(((tap * 8 + cb) * 16 + ob) * 64 + lane)) * 8);
      }
      short8 zf[4];
#pragma unroll
      for (int wfi = 0; wfi < 4; ++wfi) {
        int wpos = wfi * 16 + m + kw;
        zf[wfi] = *reinterpret_cast<const short8*>(
            &zs[(kh * 66 + wpos) * 40 + q * 8]);
      }
#pragma unroll
      for (int of = 0; of < 4; ++of)
#pragma unroll
        for (int wfi = 0; wfi < 4; ++wfi)
          acc[of][wfi] = __builtin_amdgcn_mfma_f32_16x16x32_bf16(
              wf[of], zf[wfi], acc[of][wfi], 0, 0, 0);
    }
  }
  // Epilogue: D row = o = wave*64 + of*16 + q*4 + r, col = w = wfi*16 + m
#pragma unroll
  for (int of = 0; of < 4; ++of) {
    int o_base = wave * 64 + of * 16 + q * 4;
#pragma unroll
    for (int r = 0; r < 4; ++r) {
      int o = o_base + r;
      float sc = gm[o] * rsqrtf(vr[o] + 1e-5f);
      float sh = bt[o] + (bo[o] - mn[o]) * sc;
#pragma unroll
      for (int wfi = 0; wfi < 4; ++wfi) {
        float y = acc[of][wfi][r] * sc + sh;
        y = (y >= 0.f) ? y : 0.2f * y;
        out[(((size_t)(b * 256 + o)) * 64 + h) * 64 + wfi * 16 + m] = y;
      }
    }
  }
}

extern "C" void kernel_launch(void* const* d_in, const int* in_sizes, int n_in,
                              void* d_out, int out_size, void* d_ws,
                              size_t ws_size, hipStream_t stream) {
  (void)in_sizes; (void)n_in; (void)out_size; (void)ws_size;
  const float* x  = (const float*)d_in[0];
  const float* wq = (const float*)d_in[1];
  const float* bq = (const float*)d_in[2];
  const float* wk = (const float*)d_in[3];
  const float* bk = (const float*)d_in[4];
  const float* wv = (const float*)d_in[5];
  const float* bv = (const float*)d_in[6];
  const float* wo = (const float*)d_in[7];
  const float* bo = (const float*)d_in[8];
  const float* gm = (const float*)d_in[9];
  const float* bt = (const float*)d_in[10];
  const float* mn = (const float*)d_in[11];
  const float* vr = (const float*)d_in[12];
  float* out = (float*)d_out;

  char* ws = (char*)d_ws;
  __hip_bfloat16* qb = (__hip_bfloat16*)(ws);             // 32 MB; reused: z NHWC
  __hip_bfloat16* kb = (__hip_bfloat16*)(ws + 33554432);  // 32 MB
  float* attn = (float*)(ws + 67108864);                  // 256 KB
  __hip_bfloat16* blob = (__hip_bfloat16*)(ws + 67108864 + 262144);  // 1.18 MB
  // v lives in d_out (bf16); dead before conv_mfma overwrites d_out.
  __hip_bfloat16* vb = (__hip_bfloat16*)d_out;

  hipMemsetAsync(attn, 0, BB * 64 * 64 * sizeof(float), stream);
  wprep<<<288, 256, 0, stream>>>(wo, blob);
  qkv_gemm<<<dim3(64, 4, BB * 3), 256, 0, stream>>>(x, wq, bq, wk, bk, wv, bv,
                                                    qb, kb, vb);
  scores_kernel<<<dim3(16, BB), 256, 0, stream>>>(qb, kb, attn);
  softmax_kernel<<<dim3(64, BB), 64, 0, stream>>>(attn);
  apply_attn<<<dim3(32, BB), 256, 0, stream>>>(attn, vb, qb /* z NHWC */);
  conv_mfma<<<dim3(BB * 64), 256, 0, stream>>>(qb, blob, bo, gm, bt, mn, vr,
                                               out);
}

// Round 4
// 641.643 us; speedup vs baseline: 3.3037x; 1.6227x over previous
//
#include <hip/hip_runtime.h>
#include <hip/hip_bf16.h>

// B=16, D=256, H=64, W=64, S=4096, P=8, tokens T=64, E=D*64=16384
// Inputs/outputs FLOAT32 (per reference). Intermediates bf16.
#define BB 16
#define SS 4096

typedef __attribute__((ext_vector_type(8))) short short8;
typedef __attribute__((ext_vector_type(4))) float float4v;

__device__ __forceinline__ float bf2f(__hip_bfloat16 h) {
  return __bfloat162float(h);
}
__device__ __forceinline__ void bf16x8_to_f(uint4 u, float* f) {
  unsigned w[4] = {u.x, u.y, u.z, u.w};
#pragma unroll
  for (int i = 0; i < 4; ++i) {
    union { unsigned u; float f; } lo, hi;
    lo.u = (w[i] & 0xffffu) << 16;
    hi.u = w[i] & 0xffff0000u;
    f[2 * i] = lo.f;
    f[2 * i + 1] = hi.f;
  }
}

// ---------------------------------------------------------------------------
// K0a: QKV weight prep. Wq/Wk/Wv fp32 [o][c] -> bf16 blob in A-frag order:
// blob[((which*8+cb)*16+ob)*512 + lane*8 + j] =
//     W_which[o=ob*16+(lane&15)][c=cb*32+(lane>>4)*8+j]
// ---------------------------------------------------------------------------
__global__ __launch_bounds__(256) void wprep_qkv(
    const float* __restrict__ wq, const float* __restrict__ wk,
    const float* __restrict__ wv, __hip_bfloat16* __restrict__ blob) {
  int chunk = blockIdx.x * 256 + threadIdx.x;  // 24576 = 3*8*16*64 exact
  int lane = chunk & 63;
  int ob = (chunk >> 6) & 15;
  int cb = (chunk >> 10) & 7;
  int which = chunk >> 13;
  const float* W = (which == 0) ? wq : (which == 1) ? wk : wv;
  int o = ob * 16 + (lane & 15);
  int c0 = cb * 32 + (lane >> 4) * 8;
  const float* p = W + o * 256 + c0;
  union { uint4 u; __hip_bfloat16 h[8]; } t;
#pragma unroll
  for (int j = 0; j < 8; ++j) t.h[j] = __float2bfloat16(p[j]);
  *reinterpret_cast<uint4*>(blob + (size_t)chunk * 8) = t.u;
}

// ---------------------------------------------------------------------------
// K1: MFMA QKV GEMM. D[o][s] = sum_c W[o,c] X[b,c,s] + bias[o] -> bf16 NCHW.
// grid (64 s-tiles, B, 3 which), block 256 (4 waves; wave owns 64 o).
// K-loop: 8 cblocks of 32c; X staged fp32->bf16 into LDS [s][c] stride 40.
// ---------------------------------------------------------------------------
__global__ __launch_bounds__(256) void qkv_mfma(
    const float* __restrict__ x, const __hip_bfloat16* __restrict__ blob,
    const float* __restrict__ bq, const float* __restrict__ bk,
    const float* __restrict__ bv,
    __hip_bfloat16* __restrict__ qb, __hip_bfloat16* __restrict__ kb,
    __hip_bfloat16* __restrict__ vb) {
  __shared__ short ls[64 * 40];
  const int which = blockIdx.z;
  const int b = blockIdx.y;
  const int s0 = blockIdx.x * 64;
  const float* bias = (which == 0) ? bq : (which == 1) ? bk : bv;
  __hip_bfloat16* outb = (which == 0) ? qb : (which == 1) ? kb : vb;
  const int tid = threadIdx.x;
  const int wave = tid >> 6, lane = tid & 63;
  const int q = lane >> 4, m = lane & 15;
  const int sl = tid & 63;  // staging: s within tile
  const int cg = tid >> 6;  // staging: c-group (8 c's)
  float4v acc[4][4] = {};   // [of][sf]

  for (int cb = 0; cb < 8; ++cb) {
    __syncthreads();  // prev-iter LDS reads done before restage
    {
      const float* xp = x + ((size_t)(b * 256 + cb * 32 + cg * 8)) * SS + s0 + sl;
      union { uint4 u; __hip_bfloat16 h[8]; } t;
#pragma unroll
      for (int i = 0; i < 8; ++i)
        t.h[i] = __float2bfloat16(xp[(size_t)i * SS]);
      *reinterpret_cast<uint4*>(&ls[sl * 40 + cg * 8]) = t.u;
    }
    __syncthreads();
    short8 af[4];
#pragma unroll
    for (int of = 0; of < 4; ++of)
      af[of] = *reinterpret_cast<const short8*>(
          blob +
          ((size_t)(((which * 8 + cb) * 16 + wave * 4 + of) * 64 + lane)) * 8);
    short8 xf[4];
#pragma unroll
    for (int sf = 0; sf < 4; ++sf)
      xf[sf] = *reinterpret_cast<const short8*>(&ls[(sf * 16 + m) * 40 + q * 8]);
#pragma unroll
    for (int of = 0; of < 4; ++of)
#pragma unroll
      for (int sf = 0; sf < 4; ++sf)
        acc[of][sf] = __builtin_amdgcn_mfma_f32_16x16x32_bf16(
            af[of], xf[sf], acc[of][sf], 0, 0, 0);
  }
  // D: row = o = wave*64 + of*16 + q*4 + r, col = s = s0 + sf*16 + m
#pragma unroll
  for (int of = 0; of < 4; ++of) {
    int o_base = wave * 64 + of * 16 + q * 4;
#pragma unroll
    for (int r = 0; r < 4; ++r) {
      int o = o_base + r;
      float bi = bias[o];
      __hip_bfloat16* op = outb + ((size_t)(b * 256 + o)) * SS + s0 + m;
#pragma unroll
      for (int sf = 0; sf < 4; ++sf)
        op[sf * 16] = __float2bfloat16(acc[of][sf][r] + bi);
    }
  }
}

// ---------------------------------------------------------------------------
// K2: raw scores[b,t,t'] = sum_e q[b,t,e]*k[b,t',e] (unscaled, atomicAdd)
// ---------------------------------------------------------------------------
__global__ __launch_bounds__(256) void scores_kernel(
    const __hip_bfloat16* __restrict__ qb, const __hip_bfloat16* __restrict__ kb,
    float* __restrict__ attn) {
  __shared__ float qs[64 * 65];
  __shared__ float ks[64 * 65];
  const int b = blockIdx.y;
  const int d0 = blockIdx.x * 16;
  const int tid = threadIdx.x;
  const int tq = (tid >> 4) * 4;
  const int tk = (tid & 15) * 4;
  float acc[4][4] = {};

  for (int dd = 0; dd < 16; ++dd) {
    const int d = d0 + dd;
    const __hip_bfloat16* qp = qb + ((size_t)(b * 256 + d)) * SS;
    const __hip_bfloat16* kp = kb + ((size_t)(b * 256 + d)) * SS;
#pragma unroll
    for (int j = 0; j < 2; ++j) {
      int base = (j * 256 + tid) * 8;
      int h = base >> 6, w = base & 63;
      int t = (h >> 3) * 8 + (w >> 3);
      int off = (h & 7) * 8;
      float f[8];
      bf16x8_to_f(*reinterpret_cast<const uint4*>(qp + base), f);
#pragma unroll
      for (int e = 0; e < 8; ++e) qs[t * 65 + off + e] = f[e];
      bf16x8_to_f(*reinterpret_cast<const uint4*>(kp + base), f);
#pragma unroll
      for (int e = 0; e < 8; ++e) ks[t * 65 + off + e] = f[e];
    }
    __syncthreads();
#pragma unroll 8
    for (int off = 0; off < 64; ++off) {
      float a[4], bb[4];
#pragma unroll
      for (int i = 0; i < 4; ++i) a[i] = qs[(tq + i) * 65 + off];
#pragma unroll
      for (int j = 0; j < 4; ++j) bb[j] = ks[(tk + j) * 65 + off];
#pragma unroll
      for (int i = 0; i < 4; ++i)
#pragma unroll
        for (int j = 0; j < 4; ++j) acc[i][j] += a[i] * bb[j];
    }
    __syncthreads();
  }
#pragma unroll
  for (int i = 0; i < 4; ++i)
#pragma unroll
    for (int j = 0; j < 4; ++j)
      atomicAdd(&attn[(b * 64 + tq + i) * 64 + tk + j], acc[i][j]);
}

// ---------------------------------------------------------------------------
// K3: softmax over t' with scale 1/128. grid (64 t, B), block 64.
// ---------------------------------------------------------------------------
__global__ __launch_bounds__(64) void softmax_kernel(float* __restrict__ attn) {
  const int t = blockIdx.x;
  const int b = blockIdx.y;
  const int lane = threadIdx.x;
  float* row = attn + (b * 64 + t) * 64;
  float v = row[lane] * 0.0078125f;  // 1/sqrt(16384)
  float m = v;
#pragma unroll
  for (int off = 32; off >= 1; off >>= 1) m = fmaxf(m, __shfl_xor(m, off));
  float e = __expf(v - m);
  float s = e;
#pragma unroll
  for (int off = 32; off >= 1; off >>= 1) s += __shfl_xor(s, off);
  row[lane] = e / s;
}

// ---------------------------------------------------------------------------
// K4: z = attn @ v, written NHWC: z[((b*64+h)*64+w)*256 + d]  (bf16)
// ---------------------------------------------------------------------------
__global__ __launch_bounds__(256) void apply_attn(
    const float* __restrict__ attn, const __hip_bfloat16* __restrict__ vb,
    __hip_bfloat16* __restrict__ zb) {
  __shared__ float A[64 * 65];
  __shared__ float Vp[64 * 65];
  const int b = blockIdx.y;
  const int d0 = blockIdx.x * 8;
  const int tid = threadIdx.x;
#pragma unroll
  for (int j = 0; j < 16; ++j) {
    int idx = j * 256 + tid;
    A[(idx >> 6) * 65 + (idx & 63)] = attn[b * 4096 + idx];
  }
  const int t0 = (tid >> 4) * 4;
  const int f0 = (tid & 15) * 4;
  for (int ddv = 0; ddv < 8; ++ddv) {
    const int d = d0 + ddv;
    const __hip_bfloat16* vp = vb + ((size_t)(b * 256 + d)) * SS;
#pragma unroll
    for (int j = 0; j < 2; ++j) {
      int base = (j * 256 + tid) * 8;
      int h = base >> 6, w = base & 63;
      int t = (h >> 3) * 8 + (w >> 3);
      int off = (h & 7) * 8;
      float f[8];
      bf16x8_to_f(*reinterpret_cast<const uint4*>(vp + base), f);
#pragma unroll
      for (int e = 0; e < 8; ++e) Vp[t * 65 + off + e] = f[e];
    }
    __syncthreads();
    float acc[4][4] = {};
#pragma unroll 8
    for (int tp = 0; tp < 64; ++tp) {
      float a[4], vv[4];
#pragma unroll
      for (int i = 0; i < 4; ++i) a[i] = A[(t0 + i) * 65 + tp];
#pragma unroll
      for (int j = 0; j < 4; ++j) vv[j] = Vp[tp * 65 + f0 + j];
#pragma unroll
      for (int i = 0; i < 4; ++i)
#pragma unroll
        for (int j = 0; j < 4; ++j) acc[i][j] += a[i] * vv[j];
    }
#pragma unroll
    for (int i = 0; i < 4; ++i) {
      int t = t0 + i;
#pragma unroll
      for (int j = 0; j < 4; ++j) {
        int off = f0 + j;
        int h = (t >> 3) * 8 + (off >> 3);
        int w = (t & 7) * 8 + (off & 7);
        zb[((size_t)((b * 64 + h) * 64 + w)) * 256 + d] =
            __float2bfloat16(acc[i][j]);
      }
    }
    __syncthreads();
  }
}

// ---------------------------------------------------------------------------
// K5a: conv weight prep (B-frag order, see R3).
// ---------------------------------------------------------------------------
__global__ __launch_bounds__(256) void wprep(
    const float* __restrict__ wo, __hip_bfloat16* __restrict__ blob) {
  int chunk = blockIdx.x * 256 + threadIdx.x;  // 73728 = 9*8*16*64 exact
  int l = chunk & 63;
  int ob = (chunk >> 6) & 15;
  int cb = (chunk >> 10) & 7;
  int tap = chunk >> 13;
  int o = ob * 16 + (l & 15);
  int c0 = cb * 32 + (l >> 4) * 8;
  union { uint4 u; __hip_bfloat16 h[8]; } t;
#pragma unroll
  for (int j = 0; j < 8; ++j)
    t.h[j] = __float2bfloat16(wo[((size_t)(o * 256 + c0 + j)) * 9 + tap]);
  *reinterpret_cast<uint4*>(blob + (size_t)chunk * 8) = t.u;
}

// ---------------------------------------------------------------------------
// K5b: MFMA implicit-GEMM 3x3 conv + bias + BN + LeakyReLU.
// ---------------------------------------------------------------------------
__global__ __launch_bounds__(256) void conv_mfma(
    const __hip_bfloat16* __restrict__ z, const __hip_bfloat16* __restrict__ blob,
    const float* __restrict__ bo, const float* __restrict__ gm,
    const float* __restrict__ bt, const float* __restrict__ mn,
    const float* __restrict__ vr, float* __restrict__ out) {
  __shared__ short zs[3 * 66 * 40];
  const int row = blockIdx.x;  // b*64 + h
  const int b = row >> 6, h = row & 63;
  const int tid = threadIdx.x;
  const int wave = tid >> 6, lane = tid & 63;
  const int q = lane >> 4, m = lane & 15;
  float4v acc[4][4] = {};  // [of][wf]

  for (int cb = 0; cb < 8; ++cb) {
    __syncthreads();
    for (int idx = tid; idx < 792; idx += 256) {  // 3*66*4 uint4 chunks
      int cg = idx & 3;
      int t2 = idx >> 2;
      int wpos = t2 % 66;
      int r = t2 / 66;
      int h_in = h - 1 + r;
      int w_in = wpos - 1;
      uint4 val = make_uint4(0u, 0u, 0u, 0u);
      if (h_in >= 0 && h_in < 64 && w_in >= 0 && w_in < 64)
        val = *reinterpret_cast<const uint4*>(
            z + ((size_t)((b * 64 + h_in) * 64 + w_in)) * 256 + cb * 32 + cg * 8);
      *reinterpret_cast<uint4*>(&zs[(r * 66 + wpos) * 40 + cg * 8]) = val;
    }
    __syncthreads();
    for (int tap = 0; tap < 9; ++tap) {
      const int kh = tap / 3, kw = tap % 3;
      short8 wf[4];
#pragma unroll
      for (int of = 0; of < 4; ++of) {
        int ob = wave * 4 + of;
        wf[of] = *reinterpret_cast<const short8*>(
            blob + ((size_t)(((tap * 8 + cb) * 16 + ob) * 64 + lane)) * 8);
      }
      short8 zf[4];
#pragma unroll
      for (int wfi = 0; wfi < 4; ++wfi) {
        int wpos = wfi * 16 + m + kw;
        zf[wfi] = *reinterpret_cast<const short8*>(
            &zs[(kh * 66 + wpos) * 40 + q * 8]);
      }
#pragma unroll
      for (int of = 0; of < 4; ++of)
#pragma unroll
        for (int wfi = 0; wfi < 4; ++wfi)
          acc[of][wfi] = __builtin_amdgcn_mfma_f32_16x16x32_bf16(
              wf[of], zf[wfi], acc[of][wfi], 0, 0, 0);
    }
  }
#pragma unroll
  for (int of = 0; of < 4; ++of) {
    int o_base = wave * 64 + of * 16 + q * 4;
#pragma unroll
    for (int r = 0; r < 4; ++r) {
      int o = o_base + r;
      float sc = gm[o] * rsqrtf(vr[o] + 1e-5f);
      float sh = bt[o] + (bo[o] - mn[o]) * sc;
#pragma unroll
      for (int wfi = 0; wfi < 4; ++wfi) {
        float y = acc[of][wfi][r] * sc + sh;
        y = (y >= 0.f) ? y : 0.2f * y;
        out[(((size_t)(b * 256 + o)) * 64 + h) * 64 + wfi * 16 + m] = y;
      }
    }
  }
}

extern "C" void kernel_launch(void* const* d_in, const int* in_sizes, int n_in,
                              void* d_out, int out_size, void* d_ws,
                              size_t ws_size, hipStream_t stream) {
  (void)in_sizes; (void)n_in; (void)out_size; (void)ws_size;
  const float* x  = (const float*)d_in[0];
  const float* wq = (const float*)d_in[1];
  const float* bq = (const float*)d_in[2];
  const float* wk = (const float*)d_in[3];
  const float* bk = (const float*)d_in[4];
  const float* wv = (const float*)d_in[5];
  const float* bv = (const float*)d_in[6];
  const float* wo = (const float*)d_in[7];
  const float* bo = (const float*)d_in[8];
  const float* gm = (const float*)d_in[9];
  const float* bt = (const float*)d_in[10];
  const float* mn = (const float*)d_in[11];
  const float* vr = (const float*)d_in[12];
  float* out = (float*)d_out;

  char* ws = (char*)d_ws;
  __hip_bfloat16* qb = (__hip_bfloat16*)(ws);             // 32 MB; reused: z NHWC
  __hip_bfloat16* kb = (__hip_bfloat16*)(ws + 33554432);  // 32 MB
  float* attn = (float*)(ws + 67108864);                  // 256 KB
  __hip_bfloat16* blob = (__hip_bfloat16*)(ws + 67371008);      // 1.125 MB (conv W)
  __hip_bfloat16* blob_a = (__hip_bfloat16*)(ws + 68550656);    // 384 KB (qkv W)
  // v lives in d_out (bf16); dead before conv_mfma overwrites d_out.
  __hip_bfloat16* vb = (__hip_bfloat16*)d_out;

  hipMemsetAsync(attn, 0, BB * 64 * 64 * sizeof(float), stream);
  wprep<<<288, 256, 0, stream>>>(wo, blob);
  wprep_qkv<<<96, 256, 0, stream>>>(wq, wk, wv, blob_a);
  qkv_mfma<<<dim3(64, BB, 3), 256, 0, stream>>>(x, blob_a, bq, bk, bv,
                                                qb, kb, vb);
  scores_kernel<<<dim3(16, BB), 256, 0, stream>>>(qb, kb, attn);
  softmax_kernel<<<dim3(64, BB), 64, 0, stream>>>(attn);
  apply_attn<<<dim3(32, BB), 256, 0, stream>>>(attn, vb, qb /* z NHWC */);
  conv_mfma<<<dim3(BB * 64), 256, 0, stream>>>(qb, blob, bo, gm, bt, mn, vr,
                                               out);
}

// Round 5
// 410.202 us; speedup vs baseline: 5.1677x; 1.5642x over previous
//
#include <hip/hip_runtime.h>
#include <hip/hip_bf16.h>

// B=16, D=256, H=64, W=64, S=4096, P=8, tokens T=64, E=D*64=16384
// Inputs/outputs FLOAT32 (per reference). Intermediates bf16.
#define BB 16
#define SS 4096

typedef __attribute__((ext_vector_type(8))) short short8;
typedef __attribute__((ext_vector_type(4))) float float4v;

// ---------------------------------------------------------------------------
// K0a: QKV weight prep. Wq/Wk/Wv fp32 [o][c] -> bf16 blob in A-frag order.
// ---------------------------------------------------------------------------
__global__ __launch_bounds__(256) void wprep_qkv(
    const float* __restrict__ wq, const float* __restrict__ wk,
    const float* __restrict__ wv, __hip_bfloat16* __restrict__ blob) {
  int chunk = blockIdx.x * 256 + threadIdx.x;  // 24576 = 3*8*16*64 exact
  int lane = chunk & 63;
  int ob = (chunk >> 6) & 15;
  int cb = (chunk >> 10) & 7;
  int which = chunk >> 13;
  const float* W = (which == 0) ? wq : (which == 1) ? wk : wv;
  int o = ob * 16 + (lane & 15);
  int c0 = cb * 32 + (lane >> 4) * 8;
  const float* p = W + o * 256 + c0;
  union { uint4 u; __hip_bfloat16 h[8]; } t;
#pragma unroll
  for (int j = 0; j < 8; ++j) t.h[j] = __float2bfloat16(p[j]);
  *reinterpret_cast<uint4*>(blob + (size_t)chunk * 8) = t.u;
}

// ---------------------------------------------------------------------------
// K1: MFMA QKV GEMM. D[o][s] = sum_c W[o,c] X[b,c,s] + bias[o].
// q,k -> bf16 NCHW. v -> bf16 NHWC (packed 4-o 8B stores -> full lines).
// grid (64 s-tiles, B, 3 which), block 256.
// ---------------------------------------------------------------------------
__global__ __launch_bounds__(256) void qkv_mfma(
    const float* __restrict__ x, const __hip_bfloat16* __restrict__ blob,
    const float* __restrict__ bq, const float* __restrict__ bk,
    const float* __restrict__ bv,
    __hip_bfloat16* __restrict__ qb, __hip_bfloat16* __restrict__ kb,
    __hip_bfloat16* __restrict__ vb) {
  __shared__ short ls[64 * 40];
  const int which = blockIdx.z;
  const int b = blockIdx.y;
  const int s0 = blockIdx.x * 64;
  const float* bias = (which == 0) ? bq : (which == 1) ? bk : bv;
  __hip_bfloat16* outb = (which == 0) ? qb : kb;  // v handled separately
  const int tid = threadIdx.x;
  const int wave = tid >> 6, lane = tid & 63;
  const int q = lane >> 4, m = lane & 15;
  const int sl = tid & 63;
  const int cg = tid >> 6;
  float4v acc[4][4] = {};  // [of][sf]

  for (int cb = 0; cb < 8; ++cb) {
    __syncthreads();
    {
      const float* xp = x + ((size_t)(b * 256 + cb * 32 + cg * 8)) * SS + s0 + sl;
      union { uint4 u; __hip_bfloat16 h[8]; } t;
#pragma unroll
      for (int i = 0; i < 8; ++i)
        t.h[i] = __float2bfloat16(xp[(size_t)i * SS]);
      *reinterpret_cast<uint4*>(&ls[sl * 40 + cg * 8]) = t.u;
    }
    __syncthreads();
    short8 af[4];
#pragma unroll
    for (int of = 0; of < 4; ++of)
      af[of] = *reinterpret_cast<const short8*>(
          blob +
          ((size_t)(((which * 8 + cb) * 16 + wave * 4 + of) * 64 + lane)) * 8);
    short8 xf[4];
#pragma unroll
    for (int sf = 0; sf < 4; ++sf)
      xf[sf] = *reinterpret_cast<const short8*>(&ls[(sf * 16 + m) * 40 + q * 8]);
#pragma unroll
    for (int of = 0; of < 4; ++of)
#pragma unroll
      for (int sf = 0; sf < 4; ++sf)
        acc[of][sf] = __builtin_amdgcn_mfma_f32_16x16x32_bf16(
            af[of], xf[sf], acc[of][sf], 0, 0, 0);
  }
  if (which == 2) {
    // v NHWC: vb[((b*64+h)*64+w)*256 + o], pack r=0..3 (4 consecutive o).
    const int h = s0 >> 6;
#pragma unroll
    for (int of = 0; of < 4; ++of) {
      int o_base = wave * 64 + of * 16 + q * 4;
#pragma unroll
      for (int sf = 0; sf < 4; ++sf) {
        int w = sf * 16 + m;
        union { uint2 u; __hip_bfloat16 hh[4]; } t;
#pragma unroll
        for (int r = 0; r < 4; ++r)
          t.hh[r] = __float2bfloat16(acc[of][sf][r] + bias[o_base + r]);
        *reinterpret_cast<uint2*>(
            vb + ((size_t)((b * 64 + h) * 64 + w)) * 256 + o_base) = t.u;
      }
    }
  } else {
    // NCHW: row = o, col = s
#pragma unroll
    for (int of = 0; of < 4; ++of) {
      int o_base = wave * 64 + of * 16 + q * 4;
#pragma unroll
      for (int r = 0; r < 4; ++r) {
        int o = o_base + r;
        float bi = bias[o];
        __hip_bfloat16* op = outb + ((size_t)(b * 256 + o)) * SS + s0 + m;
#pragma unroll
        for (int sf = 0; sf < 4; ++sf)
          op[sf * 16] = __float2bfloat16(acc[of][sf][r] + bi);
      }
    }
  }
}

// ---------------------------------------------------------------------------
// K2: MFMA scores. scores[b][t][t'] += sum over e-slice of q.k (f32 atomics).
// q,k NCHW bf16: 8 contiguous w = 8 contiguous k per lane (direct global
// frags, no LDS). grid (16 d-chunks, B), block 256; wave owns mtile=wave.
// e = d*64 + oh*8 + ow; k-step = (d, oh half): oh = khalf*4 + q, j = ow.
// ---------------------------------------------------------------------------
__global__ __launch_bounds__(256) void scores_mfma(
    const __hip_bfloat16* __restrict__ qb, const __hip_bfloat16* __restrict__ kb,
    float* __restrict__ scores) {
  const int b = blockIdx.y;
  const int d0 = blockIdx.x * 16;
  const int tid = threadIdx.x;
  const int wave = tid >> 6, lane = tid & 63;
  const int q = lane >> 4, m = lane & 15;
  const int t = wave * 16 + m;           // A row (this wave's mtile)
  const int arow = (t >> 3) * 8;         // h-patch base for t
  const int acol = (t & 7) * 8;          // w base for t
  float4v acc[4] = {};                   // [ntile]

  for (int dd = 0; dd < 16; ++dd) {
    const int d = d0 + dd;
    const __hip_bfloat16* qp = qb + ((size_t)(b * 256 + d)) * SS;
    const __hip_bfloat16* kp = kb + ((size_t)(b * 256 + d)) * SS;
#pragma unroll
    for (int khalf = 0; khalf < 2; ++khalf) {
      const int oh = khalf * 4 + q;
      short8 af = *reinterpret_cast<const short8*>(
          qp + (arow + oh) * 64 + acol);
      short8 bf[4];
#pragma unroll
      for (int nt = 0; nt < 4; ++nt) {
        int tp = nt * 16 + m;
        bf[nt] = *reinterpret_cast<const short8*>(
            kp + ((tp >> 3) * 8 + oh) * 64 + (tp & 7) * 8);
      }
#pragma unroll
      for (int nt = 0; nt < 4; ++nt)
        acc[nt] = __builtin_amdgcn_mfma_f32_16x16x32_bf16(af, bf[nt], acc[nt],
                                                          0, 0, 0);
    }
  }
  // D: row = t = wave*16 + q*4 + r, col = t' = nt*16 + m
#pragma unroll
  for (int nt = 0; nt < 4; ++nt)
#pragma unroll
    for (int r = 0; r < 4; ++r)
      atomicAdd(&scores[(b * 64 + wave * 16 + q * 4 + r) * 64 + nt * 16 + m],
                acc[nt][r]);
}

// ---------------------------------------------------------------------------
// K3: softmax over t' with scale 1/128; writes bf16 attn matrix.
// ---------------------------------------------------------------------------
__global__ __launch_bounds__(64) void softmax_kernel(
    const float* __restrict__ scores, __hip_bfloat16* __restrict__ attnb) {
  const int t = blockIdx.x;
  const int b = blockIdx.y;
  const int lane = threadIdx.x;
  float v = scores[(b * 64 + t) * 64 + lane] * 0.0078125f;  // 1/sqrt(16384)
  float m = v;
#pragma unroll
  for (int off = 32; off >= 1; off >>= 1) m = fmaxf(m, __shfl_xor(m, off));
  float e = __expf(v - m);
  float s = e;
#pragma unroll
  for (int off = 32; off >= 1; off >>= 1) s += __shfl_xor(s, off);
  attnb[(b * 64 + t) * 64 + lane] = __float2bfloat16(e / s);
}

// ---------------------------------------------------------------------------
// K4: MFMA apply. One block per (b, off): z[t][d] = sum_t' attn[t][t'] V[t'][d]
// A = attn bf16 (direct global frags). B = V rows (NHWC, staged to LDS,
// u16 column gathers; stride 268 de-conflicts). z NHWC, d-contiguous stores.
// ---------------------------------------------------------------------------
__global__ __launch_bounds__(256) void apply_mfma(
    const __hip_bfloat16* __restrict__ attnb, const __hip_bfloat16* __restrict__ vb,
    __hip_bfloat16* __restrict__ zb) {
  __shared__ short Vs[64][268];
  const int off = blockIdx.x;
  const int b = blockIdx.y;
  const int oh = off >> 3, ow = off & 7;
  const int tid = threadIdx.x;
  // stage V tile: rows t' (64) x 256 d, 2048 uint4 chunks
#pragma unroll
  for (int i = 0; i < 8; ++i) {
    int chunk = i * 256 + tid;
    int tp = chunk >> 5;
    int cg = chunk & 31;
    int hh = (tp >> 3) * 8 + oh;
    int wwp = (tp & 7) * 8 + ow;
    uint4 val = *reinterpret_cast<const uint4*>(
        vb + ((size_t)((b * 64 + hh) * 64 + wwp)) * 256 + cg * 8);
    *reinterpret_cast<uint4*>(&Vs[tp][cg * 8]) = val;
  }
  __syncthreads();
  const int wave = tid >> 6, lane = tid & 63;
  const int q = lane >> 4, m = lane & 15;
  float4v acc[4][4] = {};  // [mtile][ntile]
#pragma unroll
  for (int ks = 0; ks < 2; ++ks) {
    short8 af[4];
#pragma unroll
    for (int mt = 0; mt < 4; ++mt)
      af[mt] = *reinterpret_cast<const short8*>(
          attnb + (b * 64 + mt * 16 + m) * 64 + ks * 32 + q * 8);
    short8 bf[4];
#pragma unroll
    for (int nt = 0; nt < 4; ++nt) {
      int d = wave * 64 + nt * 16 + m;
      union { short8 v; short s[8]; } t;
#pragma unroll
      for (int j = 0; j < 8; ++j) t.s[j] = Vs[ks * 32 + q * 8 + j][d];
      bf[nt] = t.v;
    }
#pragma unroll
    for (int mt = 0; mt < 4; ++mt)
#pragma unroll
      for (int nt = 0; nt < 4; ++nt)
        acc[mt][nt] = __builtin_amdgcn_mfma_f32_16x16x32_bf16(
            af[mt], bf[nt], acc[mt][nt], 0, 0, 0);
  }
  // D: row = t = mt*16 + q*4 + r, col = d = wave*64 + nt*16 + m
#pragma unroll
  for (int mt = 0; mt < 4; ++mt)
#pragma unroll
    for (int r = 0; r < 4; ++r) {
      int t = mt * 16 + q * 4 + r;
      int h = (t >> 3) * 8 + oh;
      int w = (t & 7) * 8 + ow;
      __hip_bfloat16* base = zb + ((size_t)((b * 64 + h) * 64 + w)) * 256;
#pragma unroll
      for (int nt = 0; nt < 4; ++nt)
        base[wave * 64 + nt * 16 + m] = __float2bfloat16(acc[mt][nt][r]);
    }
}

// ---------------------------------------------------------------------------
// K5a: conv weight prep (B-frag order).
// ---------------------------------------------------------------------------
__global__ __launch_bounds__(256) void wprep(
    const float* __restrict__ wo, __hip_bfloat16* __restrict__ blob) {
  int chunk = blockIdx.x * 256 + threadIdx.x;  // 73728 = 9*8*16*64 exact
  int l = chunk & 63;
  int ob = (chunk >> 6) & 15;
  int cb = (chunk >> 10) & 7;
  int tap = chunk >> 13;
  int o = ob * 16 + (l & 15);
  int c0 = cb * 32 + (l >> 4) * 8;
  union { uint4 u; __hip_bfloat16 h[8]; } t;
#pragma unroll
  for (int j = 0; j < 8; ++j)
    t.h[j] = __float2bfloat16(wo[((size_t)(o * 256 + c0 + j)) * 9 + tap]);
  *reinterpret_cast<uint4*>(blob + (size_t)chunk * 8) = t.u;
}

// ---------------------------------------------------------------------------
// K5b: MFMA implicit-GEMM 3x3 conv + bias + BN + LeakyReLU.
// ---------------------------------------------------------------------------
__global__ __launch_bounds__(256) void conv_mfma(
    const __hip_bfloat16* __restrict__ z, const __hip_bfloat16* __restrict__ blob,
    const float* __restrict__ bo, const float* __restrict__ gm,
    const float* __restrict__ bt, const float* __restrict__ mn,
    const float* __restrict__ vr, float* __restrict__ out) {
  __shared__ short zs[3 * 66 * 40];
  const int row = blockIdx.x;  // b*64 + h
  const int b = row >> 6, h = row & 63;
  const int tid = threadIdx.x;
  const int wave = tid >> 6, lane = tid & 63;
  const int q = lane >> 4, m = lane & 15;
  float4v acc[4][4] = {};  // [of][wf]

  for (int cb = 0; cb < 8; ++cb) {
    __syncthreads();
    for (int idx = tid; idx < 792; idx += 256) {  // 3*66*4 uint4 chunks
      int cg = idx & 3;
      int t2 = idx >> 2;
      int wpos = t2 % 66;
      int r = t2 / 66;
      int h_in = h - 1 + r;
      int w_in = wpos - 1;
      uint4 val = make_uint4(0u, 0u, 0u, 0u);
      if (h_in >= 0 && h_in < 64 && w_in >= 0 && w_in < 64)
        val = *reinterpret_cast<const uint4*>(
            z + ((size_t)((b * 64 + h_in) * 64 + w_in)) * 256 + cb * 32 + cg * 8);
      *reinterpret_cast<uint4*>(&zs[(r * 66 + wpos) * 40 + cg * 8]) = val;
    }
    __syncthreads();
    for (int tap = 0; tap < 9; ++tap) {
      const int kh = tap / 3, kw = tap % 3;
      short8 wf[4];
#pragma unroll
      for (int of = 0; of < 4; ++of) {
        int ob = wave * 4 + of;
        wf[of] = *reinterpret_cast<const short8*>(
            blob + ((size_t)(((tap * 8 + cb) * 16 + ob) * 64 + lane)) * 8);
      }
      short8 zf[4];
#pragma unroll
      for (int wfi = 0; wfi < 4; ++wfi) {
        int wpos = wfi * 16 + m + kw;
        zf[wfi] = *reinterpret_cast<const short8*>(
            &zs[(kh * 66 + wpos) * 40 + q * 8]);
      }
#pragma unroll
      for (int of = 0; of < 4; ++of)
#pragma unroll
        for (int wfi = 0; wfi < 4; ++wfi)
          acc[of][wfi] = __builtin_amdgcn_mfma_f32_16x16x32_bf16(
              wf[of], zf[wfi], acc[of][wfi], 0, 0, 0);
    }
  }
#pragma unroll
  for (int of = 0; of < 4; ++of) {
    int o_base = wave * 64 + of * 16 + q * 4;
#pragma unroll
    for (int r = 0; r < 4; ++r) {
      int o = o_base + r;
      float sc = gm[o] * rsqrtf(vr[o] + 1e-5f);
      float sh = bt[o] + (bo[o] - mn[o]) * sc;
#pragma unroll
      for (int wfi = 0; wfi < 4; ++wfi) {
        float y = acc[of][wfi][r] * sc + sh;
        y = (y >= 0.f) ? y : 0.2f * y;
        out[(((size_t)(b * 256 + o)) * 64 + h) * 64 + wfi * 16 + m] = y;
      }
    }
  }
}

extern "C" void kernel_launch(void* const* d_in, const int* in_sizes, int n_in,
                              void* d_out, int out_size, void* d_ws,
                              size_t ws_size, hipStream_t stream) {
  (void)in_sizes; (void)n_in; (void)out_size; (void)ws_size;
  const float* x  = (const float*)d_in[0];
  const float* wq = (const float*)d_in[1];
  const float* bq = (const float*)d_in[2];
  const float* wk = (const float*)d_in[3];
  const float* bk = (const float*)d_in[4];
  const float* wv = (const float*)d_in[5];
  const float* bv = (const float*)d_in[6];
  const float* wo = (const float*)d_in[7];
  const float* bo = (const float*)d_in[8];
  const float* gm = (const float*)d_in[9];
  const float* bt = (const float*)d_in[10];
  const float* mn = (const float*)d_in[11];
  const float* vr = (const float*)d_in[12];
  float* out = (float*)d_out;

  char* ws = (char*)d_ws;
  __hip_bfloat16* qb = (__hip_bfloat16*)(ws);             // 32 MB q NCHW; reused: z NHWC
  __hip_bfloat16* kb = (__hip_bfloat16*)(ws + 33554432);  // 32 MB k NCHW
  float* scores = (float*)(ws + 67108864);                // 256 KB f32
  __hip_bfloat16* attnb = (__hip_bfloat16*)(ws + 67371008);  // 128 KB bf16
  __hip_bfloat16* blob = (__hip_bfloat16*)(ws + 67502080);   // 1.125 MB conv W
  // v NHWC bf16 in d_out[0..32MB); qkv W blob in d_out[32MB..32MB+384KB).
  // Both dead before conv_mfma overwrites d_out.
  __hip_bfloat16* vb = (__hip_bfloat16*)d_out;
  __hip_bfloat16* blob_a = (__hip_bfloat16*)((char*)d_out + 33554432);

  hipMemsetAsync(scores, 0, BB * 64 * 64 * sizeof(float), stream);
  wprep<<<288, 256, 0, stream>>>(wo, blob);
  wprep_qkv<<<96, 256, 0, stream>>>(wq, wk, wv, blob_a);
  qkv_mfma<<<dim3(64, BB, 3), 256, 0, stream>>>(x, blob_a, bq, bk, bv,
                                                qb, kb, vb);
  scores_mfma<<<dim3(16, BB), 256, 0, stream>>>(qb, kb, scores);
  softmax_kernel<<<dim3(64, BB), 64, 0, stream>>>(scores, attnb);
  apply_mfma<<<dim3(64, BB), 256, 0, stream>>>(attnb, vb, qb /* z NHWC */);
  conv_mfma<<<dim3(BB * 64), 256, 0, stream>>>(qb, blob, bo, gm, bt, mn, vr,
                                               out);
}

// Round 6
// 335.194 us; speedup vs baseline: 6.3241x; 1.2238x over previous
//
#include <hip/hip_runtime.h>
#include <hip/hip_bf16.h>

// B=16, D=256, H=64, W=64, S=4096, P=8, tokens T=64, E=D*64=16384
// Inputs/outputs FLOAT32 (per reference). Intermediates bf16.
#define BB 16
#define SS 4096

typedef __attribute__((ext_vector_type(8))) short short8;
typedef __attribute__((ext_vector_type(4))) float float4v;

// ---------------------------------------------------------------------------
// K0a: QKV weight prep. Wq/Wk/Wv fp32 [o][c] -> bf16 blob in A-frag order.
// ---------------------------------------------------------------------------
__global__ __launch_bounds__(256) void wprep_qkv(
    const float* __restrict__ wq, const float* __restrict__ wk,
    const float* __restrict__ wv, __hip_bfloat16* __restrict__ blob) {
  int chunk = blockIdx.x * 256 + threadIdx.x;  // 24576 = 3*8*16*64 exact
  int lane = chunk & 63;
  int ob = (chunk >> 6) & 15;
  int cb = (chunk >> 10) & 7;
  int which = chunk >> 13;
  const float* W = (which == 0) ? wq : (which == 1) ? wk : wv;
  int o = ob * 16 + (lane & 15);
  int c0 = cb * 32 + (lane >> 4) * 8;
  const float* p = W + o * 256 + c0;
  union { uint4 u; __hip_bfloat16 h[8]; } t;
#pragma unroll
  for (int j = 0; j < 8; ++j) t.h[j] = __float2bfloat16(p[j]);
  *reinterpret_cast<uint4*>(blob + (size_t)chunk * 8) = t.u;
}

// ---------------------------------------------------------------------------
// K1: MFMA QKV GEMM. D[o][s] = sum_c W[o,c] X[b,c,s] + bias[o].
// q,k -> bf16 NCHW. v -> bf16 NHWC (packed 4-o 8B stores -> full lines).
// grid (64 s-tiles, B, 3 which), block 256.
// ---------------------------------------------------------------------------
__global__ __launch_bounds__(256) void qkv_mfma(
    const float* __restrict__ x, const __hip_bfloat16* __restrict__ blob,
    const float* __restrict__ bq, const float* __restrict__ bk,
    const float* __restrict__ bv,
    __hip_bfloat16* __restrict__ qb, __hip_bfloat16* __restrict__ kb,
    __hip_bfloat16* __restrict__ vb) {
  __shared__ short ls[64 * 40];
  const int which = blockIdx.z;
  const int b = blockIdx.y;
  const int s0 = blockIdx.x * 64;
  const float* bias = (which == 0) ? bq : (which == 1) ? bk : bv;
  __hip_bfloat16* outb = (which == 0) ? qb : kb;  // v handled separately
  const int tid = threadIdx.x;
  const int wave = tid >> 6, lane = tid & 63;
  const int q = lane >> 4, m = lane & 15;
  const int sl = tid & 63;
  const int cg = tid >> 6;
  float4v acc[4][4] = {};  // [of][sf]

  for (int cb = 0; cb < 8; ++cb) {
    __syncthreads();
    {
      const float* xp = x + ((size_t)(b * 256 + cb * 32 + cg * 8)) * SS + s0 + sl;
      union { uint4 u; __hip_bfloat16 h[8]; } t;
#pragma unroll
      for (int i = 0; i < 8; ++i)
        t.h[i] = __float2bfloat16(xp[(size_t)i * SS]);
      *reinterpret_cast<uint4*>(&ls[sl * 40 + cg * 8]) = t.u;
    }
    __syncthreads();
    short8 af[4];
#pragma unroll
    for (int of = 0; of < 4; ++of)
      af[of] = *reinterpret_cast<const short8*>(
          blob +
          ((size_t)(((which * 8 + cb) * 16 + wave * 4 + of) * 64 + lane)) * 8);
    short8 xf[4];
#pragma unroll
    for (int sf = 0; sf < 4; ++sf)
      xf[sf] = *reinterpret_cast<const short8*>(&ls[(sf * 16 + m) * 40 + q * 8]);
#pragma unroll
    for (int of = 0; of < 4; ++of)
#pragma unroll
      for (int sf = 0; sf < 4; ++sf)
        acc[of][sf] = __builtin_amdgcn_mfma_f32_16x16x32_bf16(
            af[of], xf[sf], acc[of][sf], 0, 0, 0);
  }
  if (which == 2) {
    // v NHWC: vb[((b*64+h)*64+w)*256 + o], pack r=0..3 (4 consecutive o).
    const int h = s0 >> 6;
#pragma unroll
    for (int of = 0; of < 4; ++of) {
      int o_base = wave * 64 + of * 16 + q * 4;
#pragma unroll
      for (int sf = 0; sf < 4; ++sf) {
        int w = sf * 16 + m;
        union { uint2 u; __hip_bfloat16 hh[4]; } t;
#pragma unroll
        for (int r = 0; r < 4; ++r)
          t.hh[r] = __float2bfloat16(acc[of][sf][r] + bias[o_base + r]);
        *reinterpret_cast<uint2*>(
            vb + ((size_t)((b * 64 + h) * 64 + w)) * 256 + o_base) = t.u;
      }
    }
  } else {
    // NCHW: row = o, col = s
#pragma unroll
    for (int of = 0; of < 4; ++of) {
      int o_base = wave * 64 + of * 16 + q * 4;
#pragma unroll
      for (int r = 0; r < 4; ++r) {
        int o = o_base + r;
        float bi = bias[o];
        __hip_bfloat16* op = outb + ((size_t)(b * 256 + o)) * SS + s0 + m;
#pragma unroll
        for (int sf = 0; sf < 4; ++sf)
          op[sf * 16] = __float2bfloat16(acc[of][sf][r] + bi);
      }
    }
  }
}

// ---------------------------------------------------------------------------
// K2: MFMA scores. scores[b][t][t'] += per-d-chunk partials (f32 atomics).
// ---------------------------------------------------------------------------
__global__ __launch_bounds__(256) void scores_mfma(
    const __hip_bfloat16* __restrict__ qb, const __hip_bfloat16* __restrict__ kb,
    float* __restrict__ scores) {
  const int b = blockIdx.y;
  const int d0 = blockIdx.x * 16;
  const int tid = threadIdx.x;
  const int wave = tid >> 6, lane = tid & 63;
  const int q = lane >> 4, m = lane & 15;
  const int t = wave * 16 + m;
  const int arow = (t >> 3) * 8;
  const int acol = (t & 7) * 8;
  float4v acc[4] = {};

  for (int dd = 0; dd < 16; ++dd) {
    const int d = d0 + dd;
    const __hip_bfloat16* qp = qb + ((size_t)(b * 256 + d)) * SS;
    const __hip_bfloat16* kp = kb + ((size_t)(b * 256 + d)) * SS;
#pragma unroll
    for (int khalf = 0; khalf < 2; ++khalf) {
      const int oh = khalf * 4 + q;
      short8 af = *reinterpret_cast<const short8*>(
          qp + (arow + oh) * 64 + acol);
      short8 bf[4];
#pragma unroll
      for (int nt = 0; nt < 4; ++nt) {
        int tp = nt * 16 + m;
        bf[nt] = *reinterpret_cast<const short8*>(
            kp + ((tp >> 3) * 8 + oh) * 64 + (tp & 7) * 8);
      }
#pragma unroll
      for (int nt = 0; nt < 4; ++nt)
        acc[nt] = __builtin_amdgcn_mfma_f32_16x16x32_bf16(af, bf[nt], acc[nt],
                                                          0, 0, 0);
    }
  }
#pragma unroll
  for (int nt = 0; nt < 4; ++nt)
#pragma unroll
    for (int r = 0; r < 4; ++r)
      atomicAdd(&scores[(b * 64 + wave * 16 + q * 4 + r) * 64 + nt * 16 + m],
                acc[nt][r]);
}

// ---------------------------------------------------------------------------
// K3: softmax over t' with scale 1/128; writes bf16 attn matrix.
// ---------------------------------------------------------------------------
__global__ __launch_bounds__(64) void softmax_kernel(
    const float* __restrict__ scores, __hip_bfloat16* __restrict__ attnb) {
  const int t = blockIdx.x;
  const int b = blockIdx.y;
  const int lane = threadIdx.x;
  float v = scores[(b * 64 + t) * 64 + lane] * 0.0078125f;  // 1/sqrt(16384)
  float m = v;
#pragma unroll
  for (int off = 32; off >= 1; off >>= 1) m = fmaxf(m, __shfl_xor(m, off));
  float e = __expf(v - m);
  float s = e;
#pragma unroll
  for (int off = 32; off >= 1; off >>= 1) s += __shfl_xor(s, off);
  attnb[(b * 64 + t) * 64 + lane] = __float2bfloat16(e / s);
}

// ---------------------------------------------------------------------------
// K4: MFMA apply. z[t][d] = sum_t' attn[t][t'] V[t'][d]; z NHWC bf16.
// ---------------------------------------------------------------------------
__global__ __launch_bounds__(256) void apply_mfma(
    const __hip_bfloat16* __restrict__ attnb, const __hip_bfloat16* __restrict__ vb,
    __hip_bfloat16* __restrict__ zb) {
  __shared__ short Vs[64][268];
  const int off = blockIdx.x;
  const int b = blockIdx.y;
  const int oh = off >> 3, ow = off & 7;
  const int tid = threadIdx.x;
#pragma unroll
  for (int i = 0; i < 8; ++i) {
    int chunk = i * 256 + tid;
    int tp = chunk >> 5;
    int cg = chunk & 31;
    int hh = (tp >> 3) * 8 + oh;
    int wwp = (tp & 7) * 8 + ow;
    uint4 val = *reinterpret_cast<const uint4*>(
        vb + ((size_t)((b * 64 + hh) * 64 + wwp)) * 256 + cg * 8);
    *reinterpret_cast<uint4*>(&Vs[tp][cg * 8]) = val;
  }
  __syncthreads();
  const int wave = tid >> 6, lane = tid & 63;
  const int q = lane >> 4, m = lane & 15;
  float4v acc[4][4] = {};
#pragma unroll
  for (int ks = 0; ks < 2; ++ks) {
    short8 af[4];
#pragma unroll
    for (int mt = 0; mt < 4; ++mt)
      af[mt] = *reinterpret_cast<const short8*>(
          attnb + (b * 64 + mt * 16 + m) * 64 + ks * 32 + q * 8);
    short8 bf[4];
#pragma unroll
    for (int nt = 0; nt < 4; ++nt) {
      int d = wave * 64 + nt * 16 + m;
      union { short8 v; short s[8]; } t;
#pragma unroll
      for (int j = 0; j < 8; ++j) t.s[j] = Vs[ks * 32 + q * 8 + j][d];
      bf[nt] = t.v;
    }
#pragma unroll
    for (int mt = 0; mt < 4; ++mt)
#pragma unroll
      for (int nt = 0; nt < 4; ++nt)
        acc[mt][nt] = __builtin_amdgcn_mfma_f32_16x16x32_bf16(
            af[mt], bf[nt], acc[mt][nt], 0, 0, 0);
  }
#pragma unroll
  for (int mt = 0; mt < 4; ++mt)
#pragma unroll
    for (int r = 0; r < 4; ++r) {
      int t = mt * 16 + q * 4 + r;
      int h = (t >> 3) * 8 + oh;
      int w = (t & 7) * 8 + ow;
      __hip_bfloat16* base = zb + ((size_t)((b * 64 + h) * 64 + w)) * 256;
#pragma unroll
      for (int nt = 0; nt < 4; ++nt)
        base[wave * 64 + nt * 16 + m] = __float2bfloat16(acc[mt][nt][r]);
    }
}

// ---------------------------------------------------------------------------
// K5a: conv weight prep (B-frag order).
// ---------------------------------------------------------------------------
__global__ __launch_bounds__(256) void wprep(
    const float* __restrict__ wo, __hip_bfloat16* __restrict__ blob) {
  int chunk = blockIdx.x * 256 + threadIdx.x;  // 73728 = 9*8*16*64 exact
  int l = chunk & 63;
  int ob = (chunk >> 6) & 15;
  int cb = (chunk >> 10) & 7;
  int tap = chunk >> 13;
  int o = ob * 16 + (l & 15);
  int c0 = cb * 32 + (l >> 4) * 8;
  union { uint4 u; __hip_bfloat16 h[8]; } t;
#pragma unroll
  for (int j = 0; j < 8; ++j)
    t.h[j] = __float2bfloat16(wo[((size_t)(o * 256 + c0 + j)) * 9 + tap]);
  *reinterpret_cast<uint4*>(blob + (size_t)chunk * 8) = t.u;
}

// ---------------------------------------------------------------------------
// K5b: MFMA implicit-GEMM 3x3 conv + bias + BN + LeakyReLU.
// v2: double-buffered LDS + register prefetch (1 barrier/iter, global
// latency hidden under MFMA) + XCD-aware (b,h) swizzle so h-adjacent blocks
// (sharing halo rows) land on the same XCD's L2.
// ---------------------------------------------------------------------------
__global__ __launch_bounds__(256) void conv_mfma(
    const __hip_bfloat16* __restrict__ z, const __hip_bfloat16* __restrict__ blob,
    const float* __restrict__ bo, const float* __restrict__ gm,
    const float* __restrict__ bt, const float* __restrict__ mn,
    const float* __restrict__ vr, float* __restrict__ out) {
  __shared__ short zs[2][3 * 66 * 40];
  const int idx0 = blockIdx.x;
  // XCD swizzle: xcd = idx&7 owns h-slice [8*xcd, 8*xcd+8) for all b.
  const int h = (idx0 & 7) * 8 + ((idx0 >> 3) & 7);
  const int b = idx0 >> 6;
  const int tid = threadIdx.x;
  const int wave = tid >> 6, lane = tid & 63;
  const int q = lane >> 4, m = lane & 15;
  float4v acc[4][4] = {};  // [of][wf]

  // Per-thread staging chunks: idx = tid + k*256, k<4 (792 chunks total).
  int s_r[4], s_wp[4], s_cg[4];
  bool s_ok[4];
  const __hip_bfloat16* s_base[4];
#pragma unroll
  for (int k = 0; k < 4; ++k) {
    int idx = tid + k * 256;
    bool act = idx < 792;
    int cg = idx & 3;
    int t2 = idx >> 2;
    int wpos = act ? (t2 % 66) : 0;
    int r = act ? (t2 / 66) : 0;
    int h_in = h - 1 + r;
    int w_in = wpos - 1;
    bool ok = act && h_in >= 0 && h_in < 64 && w_in >= 0 && w_in < 64;
    s_r[k] = r; s_wp[k] = wpos; s_cg[k] = cg; s_ok[k] = ok && act;
    s_ok[k] = ok;
    s_base[k] = z + ((size_t)((b * 64 + h_in) * 64 + w_in)) * 256 + cg * 8;
    if (!act) s_ok[k] = false;
    if (idx >= 792) { s_r[k] = 0; s_wp[k] = 0; s_cg[k] = 0; }
  }
  // valid-lane mask for LDS writeback (chunks >= 792 must not write)
  bool s_act[4];
#pragma unroll
  for (int k = 0; k < 4; ++k) s_act[k] = (tid + k * 256) < 792;

  uint4 pf[4];
  // prefetch cb=0
#pragma unroll
  for (int k = 0; k < 4; ++k)
    pf[k] = s_ok[k] ? *reinterpret_cast<const uint4*>(s_base[k])
                    : make_uint4(0u, 0u, 0u, 0u);
#pragma unroll
  for (int k = 0; k < 4; ++k)
    if (s_act[k])
      *reinterpret_cast<uint4*>(
          &zs[0][(s_r[k] * 66 + s_wp[k]) * 40 + s_cg[k] * 8]) = pf[k];
  __syncthreads();

  for (int cb = 0; cb < 8; ++cb) {
    const short* cur = zs[cb & 1];
    short* nxt = zs[(cb + 1) & 1];
    // issue next-chunk global loads (land during compute)
    if (cb < 7) {
#pragma unroll
      for (int k = 0; k < 4; ++k)
        pf[k] = s_ok[k] ? *reinterpret_cast<const uint4*>(
                              s_base[k] + (size_t)(cb + 1) * 32)
                        : make_uint4(0u, 0u, 0u, 0u);
    }
    // compute on cur
    for (int tap = 0; tap < 9; ++tap) {
      const int kh = tap / 3, kw = tap % 3;
      short8 wf[4];
#pragma unroll
      for (int of = 0; of < 4; ++of) {
        int ob = wave * 4 + of;
        wf[of] = *reinterpret_cast<const short8*>(
            blob + ((size_t)(((tap * 8 + cb) * 16 + ob) * 64 + lane)) * 8);
      }
      short8 zf[4];
#pragma unroll
      for (int wfi = 0; wfi < 4; ++wfi) {
        int wpos = wfi * 16 + m + kw;
        zf[wfi] = *reinterpret_cast<const short8*>(
            &cur[(kh * 66 + wpos) * 40 + q * 8]);
      }
#pragma unroll
      for (int of = 0; of < 4; ++of)
#pragma unroll
        for (int wfi = 0; wfi < 4; ++wfi)
          acc[of][wfi] = __builtin_amdgcn_mfma_f32_16x16x32_bf16(
              wf[of], zf[wfi], acc[of][wfi], 0, 0, 0);
    }
    if (cb < 7) {
#pragma unroll
      for (int k = 0; k < 4; ++k)
        if (s_act[k])
          *reinterpret_cast<uint4*>(
              &nxt[(s_r[k] * 66 + s_wp[k]) * 40 + s_cg[k] * 8]) = pf[k];
    }
    __syncthreads();
  }
#pragma unroll
  for (int of = 0; of < 4; ++of) {
    int o_base = wave * 64 + of * 16 + q * 4;
#pragma unroll
    for (int r = 0; r < 4; ++r) {
      int o = o_base + r;
      float sc = gm[o] * rsqrtf(vr[o] + 1e-5f);
      float sh = bt[o] + (bo[o] - mn[o]) * sc;
#pragma unroll
      for (int wfi = 0; wfi < 4; ++wfi) {
        float y = acc[of][wfi][r] * sc + sh;
        y = (y >= 0.f) ? y : 0.2f * y;
        out[(((size_t)(b * 256 + o)) * 64 + h) * 64 + wfi * 16 + m] = y;
      }
    }
  }
}

extern "C" void kernel_launch(void* const* d_in, const int* in_sizes, int n_in,
                              void* d_out, int out_size, void* d_ws,
                              size_t ws_size, hipStream_t stream) {
  (void)in_sizes; (void)n_in; (void)out_size; (void)ws_size;
  const float* x  = (const float*)d_in[0];
  const float* wq = (const float*)d_in[1];
  const float* bq = (const float*)d_in[2];
  const float* wk = (const float*)d_in[3];
  const float* bk = (const float*)d_in[4];
  const float* wv = (const float*)d_in[5];
  const float* bv = (const float*)d_in[6];
  const float* wo = (const float*)d_in[7];
  const float* bo = (const float*)d_in[8];
  const float* gm = (const float*)d_in[9];
  const float* bt = (const float*)d_in[10];
  const float* mn = (const float*)d_in[11];
  const float* vr = (const float*)d_in[12];
  float* out = (float*)d_out;

  char* ws = (char*)d_ws;
  __hip_bfloat16* qb = (__hip_bfloat16*)(ws);             // 32 MB q NCHW; reused: z NHWC
  __hip_bfloat16* kb = (__hip_bfloat16*)(ws + 33554432);  // 32 MB k NCHW
  float* scores = (float*)(ws + 67108864);                // 256 KB f32
  __hip_bfloat16* attnb = (__hip_bfloat16*)(ws + 67371008);  // 128 KB bf16
  __hip_bfloat16* blob = (__hip_bfloat16*)(ws + 67502080);   // 1.125 MB conv W
  // v NHWC bf16 in d_out[0..32MB); qkv W blob in d_out[32MB..32MB+384KB).
  // Both dead before conv_mfma overwrites d_out.
  __hip_bfloat16* vb = (__hip_bfloat16*)d_out;
  __hip_bfloat16* blob_a = (__hip_bfloat16*)((char*)d_out + 33554432);

  hipMemsetAsync(scores, 0, BB * 64 * 64 * sizeof(float), stream);
  wprep<<<288, 256, 0, stream>>>(wo, blob);
  wprep_qkv<<<96, 256, 0, stream>>>(wq, wk, wv, blob_a);
  qkv_mfma<<<dim3(64, BB, 3), 256, 0, stream>>>(x, blob_a, bq, bk, bv,
                                                qb, kb, vb);
  scores_mfma<<<dim3(16, BB), 256, 0, stream>>>(qb, kb, scores);
  softmax_kernel<<<dim3(64, BB), 64, 0, stream>>>(scores, attnb);
  apply_mfma<<<dim3(64, BB), 256, 0, stream>>>(attnb, vb, qb /* z NHWC */);
  conv_mfma<<<dim3(BB * 64), 256, 0, stream>>>(qb, blob, bo, gm, bt, mn, vr,
                                               out);
}